// Round 3
// baseline (893.709 us; speedup 1.0000x reference)
//
#include <hip/hip_runtime.h>

// RGCN vulnerability classifier, fp32, MI355X.
// degrees -> rsqrt -> [proj(all 8 rel fused, +out-norm) -> edge scatter(+in-norm)] x2
//   -> mean pool -> 32x2 classifier.
// Tier 1 (ws >= ~134MB, confirmed round 2): fused 8-relation projections.
// Tier 3 fallback: node-chunked per-relation path.

#define N_NODES 100000
#define N_REL   8
#define N_EDGES 80000
#define IN_F    128
#define HID     32
#define N_GRAPHS 64

constexpr int TILE = 256;   // nodes per projection block (tier-3 kernels)
constexpr int KC   = 32;
constexpr int FT   = 64;    // nodes per fused projection block

__global__ __launch_bounds__(256) void deg_kernel(const int* __restrict__ src, const int* __restrict__ dst,
                                                  int* __restrict__ dego, int* __restrict__ degi, int n_rel) {
  int i = blockIdx.x * 256 + threadIdx.x;
  if (i < n_rel * N_EDGES) {
    int r = i / N_EDGES;
    atomicAdd(&dego[r * N_NODES + src[i]], 1);
    atomicAdd(&degi[r * N_NODES + dst[i]], 1);
  }
}

__global__ __launch_bounds__(256) void rsqrt_kernel(float* __restrict__ p, int count) {
  int i = blockIdx.x * 256 + threadIdx.x;
  if (i < count) {
    int d = ((const int*)p)[i];
    p[i] = rsqrtf((float)(d < 1 ? 1 : d));
  }
}

// ---- Fused layer-1 projection: all 8 relations, one pass over x. ----
// Block 512 = 8 waves; stage 64-node x tile in LDS once; wave w does relation w.
__global__ __launch_bounds__(512) void proj1_fused(const float* __restrict__ x, const float* __restrict__ W1,
                                                   const float* __restrict__ rs_o, float* __restrict__ hw) {
  __shared__ float xs[FT][IN_F + 4];   // stride 132 words: 16B-aligned, 8-way alias on b128 (cheap)
  int t = threadIdx.x;
  int n0 = blockIdx.x * FT;
#pragma unroll
  for (int i = 0; i < (FT * IN_F / 4) / 512; i++) {   // 4 float4 per thread
    int q = t + i * 512;
    int nn = q >> 5, k4 = q & 31;
    int n = n0 + nn;
    float4 v = make_float4(0.f, 0.f, 0.f, 0.f);
    if (n < N_NODES) v = *(const float4*)&x[(size_t)n * IN_F + k4 * 4];
    *(float4*)&xs[nn][k4 * 4] = v;
  }
  __syncthreads();
  int lane = t & 63;
  int rr = t >> 6;                      // wave index == relation
  const float* __restrict__ Wr = W1 + (size_t)rr * (IN_F * HID);
  float acc[HID];
#pragma unroll
  for (int j = 0; j < HID; j++) acc[j] = 0.f;
#pragma unroll
  for (int k4 = 0; k4 < IN_F / 4; k4++) {
    float4 xv = *(const float4*)&xs[lane][k4 * 4];
    const float* wk = &Wr[(k4 * 4) * HID];
#pragma unroll
    for (int j = 0; j < HID; j++) acc[j] += xv.x * wk[j];
#pragma unroll
    for (int j = 0; j < HID; j++) acc[j] += xv.y * wk[HID + j];
#pragma unroll
    for (int j = 0; j < HID; j++) acc[j] += xv.z * wk[2 * HID + j];
#pragma unroll
    for (int j = 0; j < HID; j++) acc[j] += xv.w * wk[3 * HID + j];
  }
  int n = n0 + lane;
  if (n < N_NODES) {
    float s = rs_o[(size_t)rr * N_NODES + n];
    float* o = &hw[((size_t)rr * N_NODES + n) * HID];
#pragma unroll
    for (int j4 = 0; j4 < HID / 4; j4++) {
      float4 v = make_float4(acc[j4 * 4] * s, acc[j4 * 4 + 1] * s, acc[j4 * 4 + 2] * s, acc[j4 * 4 + 3] * s);
      *(float4*)&o[j4 * 4] = v;
    }
  }
}

// ---- Fused layer-2 projection: relu(acc1 + sum_b1) staged once, wave w does relation w. ----
__global__ __launch_bounds__(512) void proj2_fused(const float* __restrict__ acc1, const float* __restrict__ b1,
                                                   const float* __restrict__ W2, const float* __restrict__ rs_o,
                                                   float* __restrict__ hw) {
  __shared__ float hs[FT][HID + 4];    // stride 36
  int t = threadIdx.x;
  int n0 = blockIdx.x * FT;
  {
    int nn = t >> 3, j4 = t & 7;       // 512 threads = 64 nodes x 8 float4
    int n = n0 + nn;
    float4 v = make_float4(0.f, 0.f, 0.f, 0.f);
    if (n < N_NODES) v = *(const float4*)&acc1[(size_t)n * HID + j4 * 4];
    float4 sb = make_float4(0.f, 0.f, 0.f, 0.f);
#pragma unroll
    for (int q = 0; q < N_REL; q++) {
      const float* bq = &b1[q * HID + j4 * 4];
      sb.x += bq[0]; sb.y += bq[1]; sb.z += bq[2]; sb.w += bq[3];
    }
    v.x = fmaxf(v.x + sb.x, 0.f); v.y = fmaxf(v.y + sb.y, 0.f);
    v.z = fmaxf(v.z + sb.z, 0.f); v.w = fmaxf(v.w + sb.w, 0.f);
    *(float4*)&hs[nn][j4 * 4] = v;
  }
  __syncthreads();
  int lane = t & 63;
  int rr = t >> 6;
  const float* __restrict__ Wr = W2 + (size_t)rr * (HID * HID);
  float acc[HID];
#pragma unroll
  for (int j = 0; j < HID; j++) acc[j] = 0.f;
#pragma unroll
  for (int k4 = 0; k4 < HID / 4; k4++) {
    float4 hv = *(const float4*)&hs[lane][k4 * 4];
    const float* wk = &Wr[(k4 * 4) * HID];
#pragma unroll
    for (int j = 0; j < HID; j++) acc[j] += hv.x * wk[j];
#pragma unroll
    for (int j = 0; j < HID; j++) acc[j] += hv.y * wk[HID + j];
#pragma unroll
    for (int j = 0; j < HID; j++) acc[j] += hv.z * wk[2 * HID + j];
#pragma unroll
    for (int j = 0; j < HID; j++) acc[j] += hv.w * wk[3 * HID + j];
  }
  int n = n0 + lane;
  if (n < N_NODES) {
    float s = rs_o[(size_t)rr * N_NODES + n];
    float* o = &hw[((size_t)rr * N_NODES + n) * HID];
#pragma unroll
    for (int j4 = 0; j4 < HID / 4; j4++) {
      float4 v = make_float4(acc[j4 * 4] * s, acc[j4 * 4 + 1] * s, acc[j4 * 4 + 2] * s, acc[j4 * 4 + 3] * s);
      *(float4*)&o[j4 * 4] = v;
    }
  }
}

// ---- Tier-3 per-relation projection kernels (fallback) ----
__global__ __launch_bounds__(256) void proj1_kernel(const float* __restrict__ x, const float* __restrict__ W1r0,
                                                    const float* __restrict__ rs_o, float* __restrict__ hw,
                                                    int n0, int n1, int hw_nodes) {
  int rr = blockIdx.y;
  int nb = n0 + blockIdx.x * TILE;
  int t = threadIdx.x;
  __shared__ float xs[TILE][KC + 4];
  const float* __restrict__ Wr = W1r0 + (size_t)rr * (IN_F * HID);
  float acc[HID];
#pragma unroll
  for (int j = 0; j < HID; j++) acc[j] = 0.f;
  for (int kc = 0; kc < IN_F; kc += KC) {
    __syncthreads();
#pragma unroll
    for (int i = 0; i < (TILE * KC / 4) / 256; i++) {
      int q = t + i * 256;
      int nn = q >> 3, k4 = q & 7;
      int n = nb + nn;
      float4 v = make_float4(0.f, 0.f, 0.f, 0.f);
      if (n < n1) v = *(const float4*)&x[(size_t)n * IN_F + kc + k4 * 4];
      *(float4*)&xs[nn][k4 * 4] = v;
    }
    __syncthreads();
#pragma unroll
    for (int k4 = 0; k4 < KC / 4; k4++) {
      float4 xv = *(const float4*)&xs[t][k4 * 4];
      const float* wk = &Wr[(kc + k4 * 4) * HID];
#pragma unroll
      for (int j = 0; j < HID; j++) acc[j] += xv.x * wk[j];
#pragma unroll
      for (int j = 0; j < HID; j++) acc[j] += xv.y * wk[HID + j];
#pragma unroll
      for (int j = 0; j < HID; j++) acc[j] += xv.z * wk[2 * HID + j];
#pragma unroll
      for (int j = 0; j < HID; j++) acc[j] += xv.w * wk[3 * HID + j];
    }
  }
  int n = nb + t;
  if (n < n1) {
    float s = rs_o[(size_t)rr * N_NODES + n];
    float* o = &hw[((size_t)rr * hw_nodes + (n - n0)) * HID];
#pragma unroll
    for (int j4 = 0; j4 < HID / 4; j4++) {
      float4 v = make_float4(acc[j4 * 4] * s, acc[j4 * 4 + 1] * s, acc[j4 * 4 + 2] * s, acc[j4 * 4 + 3] * s);
      *(float4*)&o[j4 * 4] = v;
    }
  }
}

__global__ __launch_bounds__(256) void proj2_kernel(const float* __restrict__ acc1, const float* __restrict__ b1,
                                                    const float* __restrict__ W2r0, const float* __restrict__ rs_o,
                                                    float* __restrict__ hw, int n0, int n1, int hw_nodes) {
  int n = n0 + blockIdx.x * 256 + threadIdx.x;
  if (n >= n1) return;
  int rr = blockIdx.y;
  float h1[HID];
#pragma unroll
  for (int j4 = 0; j4 < HID / 4; j4++) {
    float4 v = *(const float4*)&acc1[(size_t)n * HID + j4 * 4];
    h1[j4 * 4 + 0] = v.x; h1[j4 * 4 + 1] = v.y; h1[j4 * 4 + 2] = v.z; h1[j4 * 4 + 3] = v.w;
  }
#pragma unroll
  for (int j = 0; j < HID; j++) {
    float sb = 0.f;
#pragma unroll
    for (int q = 0; q < N_REL; q++) sb += b1[q * HID + j];
    h1[j] = fmaxf(h1[j] + sb, 0.f);
  }
  const float* __restrict__ Wr = W2r0 + (size_t)rr * (HID * HID);
  float acc[HID];
#pragma unroll
  for (int j = 0; j < HID; j++) acc[j] = 0.f;
#pragma unroll
  for (int k = 0; k < HID; k++) {
    float hv = h1[k];
#pragma unroll
    for (int j = 0; j < HID; j++) acc[j] += hv * Wr[k * HID + j];
  }
  float s = rs_o[(size_t)rr * N_NODES + n];
  float* o = &hw[((size_t)rr * hw_nodes + (n - n0)) * HID];
#pragma unroll
  for (int j4 = 0; j4 < HID / 4; j4++) {
    float4 v = make_float4(acc[j4 * 4] * s, acc[j4 * 4 + 1] * s, acc[j4 * 4 + 2] * s, acc[j4 * 4 + 3] * s);
    *(float4*)&o[j4 * 4] = v;
  }
}

// Edge scatter: acc[d][j] += hw[rr][s-n0][j] * rs_i[rr][d] for src in [n0,n1). 32 lanes/edge.
__global__ __launch_bounds__(256) void scatter_kernel(const float* __restrict__ hw, const int* __restrict__ src,
                                                      const int* __restrict__ dst, const float* __restrict__ rs_i,
                                                      float* __restrict__ acc, int nr, int n0, int n1, int hw_nodes) {
  long i = (long)blockIdx.x * 256 + threadIdx.x;
  long total = (long)nr * N_EDGES * HID;
  if (i >= total) return;
  int j = (int)(i & (HID - 1));
  long e = i >> 5;
  int rr = (int)(e / N_EDGES);
  int ee = (int)(e - (long)rr * N_EDGES);
  int s = src[rr * N_EDGES + ee];
  if (s < n0 || s >= n1) return;
  int d = dst[rr * N_EDGES + ee];
  float v = hw[((size_t)rr * hw_nodes + (s - n0)) * HID + j] * rs_i[(size_t)rr * N_NODES + d];
  atomicAdd(&acc[(size_t)d * HID + j], v);
}

// Per-graph sum pool with LDS staging; lane = feature (conflict-free LDS atomics).
__global__ __launch_bounds__(256) void pool_kernel(const float* __restrict__ acc2, const float* __restrict__ b2,
                                                   const int* __restrict__ gid, float* __restrict__ gpool,
                                                   float* __restrict__ gcnt) {
  __shared__ float lp[N_GRAPHS * HID];
  __shared__ float lc[N_GRAPHS];
  int t = threadIdx.x;
  for (int i = t; i < N_GRAPHS * HID; i += 256) lp[i] = 0.f;
  if (t < N_GRAPHS) lc[t] = 0.f;
  __syncthreads();
  int j = t & (HID - 1);
  int grp = t >> 5;
  float sb = 0.f;
#pragma unroll
  for (int q = 0; q < N_REL; q++) sb += b2[q * HID + j];
  for (int n = blockIdx.x * 8 + grp; n < N_NODES; n += gridDim.x * 8) {
    int g = gid[n];
    float v = acc2[(size_t)n * HID + j] + sb;
    atomicAdd(&lp[g * HID + j], v);
    if (j == 0) atomicAdd(&lc[g], 1.f);
  }
  __syncthreads();
  for (int i = t; i < N_GRAPHS * HID; i += 256) atomicAdd(&gpool[i], lp[i]);
  if (t < N_GRAPHS) atomicAdd(&gcnt[t], lc[t]);
}

__global__ void final_kernel(const float* __restrict__ gpool, const float* __restrict__ gcnt,
                             const float* __restrict__ Wc, const float* __restrict__ bc,
                             float* __restrict__ out) {
  int g = threadIdx.x;
  if (g >= N_GRAPHS) return;
  float inv = 1.f / fmaxf(gcnt[g], 1.f);
  float o0 = bc[0], o1 = bc[1];
#pragma unroll
  for (int k = 0; k < HID; k++) {
    float p = gpool[g * HID + k] * inv;
    o0 += p * Wc[k * 2 + 0];
    o1 += p * Wc[k * 2 + 1];
  }
  out[g * 2 + 0] = o0;
  out[g * 2 + 1] = o1;
}

extern "C" void kernel_launch(void* const* d_in, const int* in_sizes, int n_in,
                              void* d_out, int out_size, void* d_ws, size_t ws_size,
                              hipStream_t stream) {
  const float* x  = (const float*)d_in[0];
  const int* src  = (const int*)d_in[1];
  const int* dst  = (const int*)d_in[2];
  const int* gid  = (const int*)d_in[3];
  const float* W1 = (const float*)d_in[5];
  const float* b1 = (const float*)d_in[6];
  const float* W2 = (const float*)d_in[7];
  const float* b2 = (const float*)d_in[8];
  const float* Wc = (const float*)d_in[9];
  const float* bc = (const float*)d_in[10];
  float* out = (float*)d_out;

  float* ws = (float*)d_ws;
  const size_t NF = (size_t)N_NODES * HID;
  const size_t RN = (size_t)N_REL * N_NODES;
  const size_t POOLF = N_GRAPHS * HID + N_GRAPHS;
  float* acc1  = ws;
  float* acc2  = acc1 + NF;
  float* gpool = acc2 + NF;
  float* gcnt  = gpool + N_GRAPHS * HID;
  float* rsb   = ws + (2 * NF + POOLF);
  size_t wsf = ws_size / 4;
  size_t zf = 2 * NF + POOLF;

  if (wsf >= zf + 2 * RN + N_REL * NF) {
    // ---- Tier 1: fused 8-relation projections, full hw buffer ----
    float* rs_o_all = rsb;
    float* rs_i_all = rsb + RN;
    float* hw = rsb + 2 * RN;

    size_t zb = (zf + 2 * RN) * 4; if (zb > ws_size) zb = ws_size;
    hipMemsetAsync(d_ws, 0, zb, stream);
    deg_kernel<<<(N_REL * N_EDGES + 255) / 256, 256, 0, stream>>>(src, dst, (int*)rs_o_all, (int*)rs_i_all, N_REL);
    rsqrt_kernel<<<(int)((2 * RN + 255) / 256), 256, 0, stream>>>(rs_o_all, (int)(2 * RN));

    int fblocks = (N_NODES + FT - 1) / FT;
    proj1_fused<<<fblocks, 512, 0, stream>>>(x, W1, rs_o_all, hw);
    long tot = (long)N_REL * N_EDGES * HID;
    scatter_kernel<<<(int)((tot + 255) / 256), 256, 0, stream>>>(hw, src, dst, rs_i_all, acc1,
                                                                 N_REL, 0, N_NODES, N_NODES);
    proj2_fused<<<fblocks, 512, 0, stream>>>(acc1, b1, W2, rs_o_all, hw);
    scatter_kernel<<<(int)((tot + 255) / 256), 256, 0, stream>>>(hw, src, dst, rs_i_all, acc2,
                                                                 N_REL, 0, N_NODES, N_NODES);
  } else {
    // ---- Tier 3: per-relation degrees, node-chunked hw ----
    float* rs_o = rsb;
    float* rs_i = rsb + N_NODES;
    float* hw = rsb + 2 * N_NODES;
    size_t fixed3 = zf + 2 * N_NODES;
    size_t avail = (wsf > fixed3) ? (wsf - fixed3) : 0;
    long chunk = (long)(avail / HID) & ~255L;
    if (chunk < 256) chunk = 256;
    if (chunk > N_NODES) chunk = N_NODES;

    size_t zb = zf * 4; if (zb > ws_size) zb = ws_size;
    hipMemsetAsync(d_ws, 0, zb, stream);

    for (int layer = 0; layer < 2; layer++) {
      for (int r = 0; r < N_REL; r++) {
        hipMemsetAsync(rs_o, 0, 2 * N_NODES * 4, stream);
        deg_kernel<<<(N_EDGES + 255) / 256, 256, 0, stream>>>(src + (size_t)r * N_EDGES, dst + (size_t)r * N_EDGES,
                                                              (int*)rs_o, (int*)rs_i, 1);
        rsqrt_kernel<<<(2 * N_NODES + 255) / 256, 256, 0, stream>>>(rs_o, 2 * N_NODES);
        for (long n0 = 0; n0 < N_NODES; n0 += chunk) {
          long n1 = n0 + chunk; if (n1 > N_NODES) n1 = N_NODES;
          int tiles = (int)((n1 - n0 + TILE - 1) / TILE);
          if (layer == 0)
            proj1_kernel<<<dim3(tiles, 1), 256, 0, stream>>>(x, W1 + (size_t)r * IN_F * HID, rs_o, hw,
                                                             (int)n0, (int)n1, (int)chunk);
          else
            proj2_kernel<<<dim3(tiles, 1), 256, 0, stream>>>(acc1, b1, W2 + (size_t)r * HID * HID, rs_o, hw,
                                                             (int)n0, (int)n1, (int)chunk);
          long tot = (long)N_EDGES * HID;
          scatter_kernel<<<(int)((tot + 255) / 256), 256, 0, stream>>>(hw, src + (size_t)r * N_EDGES,
                                                                       dst + (size_t)r * N_EDGES, rs_i,
                                                                       layer == 0 ? acc1 : acc2,
                                                                       1, (int)n0, (int)n1, (int)chunk);
        }
      }
    }
  }

  pool_kernel<<<256, 256, 0, stream>>>(acc2, b2, gid, gpool, gcnt);
  final_kernel<<<1, 64, 0, stream>>>(gpool, gcnt, Wc, bc, out);
}

// Round 4
// 464.928 us; speedup vs baseline: 1.9223x; 1.9223x over previous
//
#include <hip/hip_runtime.h>

// RGCN vulnerability classifier, fp32, MI355X.
// degrees -> rsqrt -> [proj(all 8 rel fused, +out-norm) -> edge scatter(+in-norm)] x2
//   -> mean pool -> 32x2 classifier.
// Fused projections: block=512 (8 waves), wave w handles relation w via
// readfirstlane (SGPR-uniform -> W goes through s_load / scalar cache),
// x tile staged once in LDS with odd stride (conflict-free b32 access).

#define N_NODES 100000
#define N_REL   8
#define N_EDGES 80000
#define IN_F    128
#define HID     32
#define N_GRAPHS 64

constexpr int TILE = 256;   // nodes per projection block (tier-3 kernels)
constexpr int KC   = 32;
constexpr int FT   = 64;    // nodes per fused projection block

__global__ __launch_bounds__(256) void deg_kernel(const int* __restrict__ src, const int* __restrict__ dst,
                                                  int* __restrict__ dego, int* __restrict__ degi, int n_rel) {
  int i = blockIdx.x * 256 + threadIdx.x;
  if (i < n_rel * N_EDGES) {
    int r = i / N_EDGES;
    atomicAdd(&dego[r * N_NODES + src[i]], 1);
    atomicAdd(&degi[r * N_NODES + dst[i]], 1);
  }
}

__global__ __launch_bounds__(256) void rsqrt_kernel(float* __restrict__ p, int count) {
  int i = blockIdx.x * 256 + threadIdx.x;
  if (i < count) {
    int d = ((const int*)p)[i];
    p[i] = rsqrtf((float)(d < 1 ? 1 : d));
  }
}

// ---- Fused layer-1 projection: all 8 relations, one pass over x. ----
__global__ __launch_bounds__(512, 8) void proj1_fused(const float* __restrict__ x, const float* __restrict__ W1,
                                                      const float* __restrict__ rs_o, float* __restrict__ hw) {
  __shared__ float xs[FT][IN_F + 1];   // stride 129 words: bank = (lane + k) % 32, conflict-free b32
  int t = threadIdx.x;
  int n0 = blockIdx.x * FT;
#pragma unroll
  for (int i = 0; i < (FT * IN_F / 4) / 512; i++) {   // 4 float4 per thread (global), scalar LDS stores
    int q = t + i * 512;
    int nn = q >> 5, k4 = q & 31;
    int n = n0 + nn;
    float4 v = make_float4(0.f, 0.f, 0.f, 0.f);
    if (n < N_NODES) v = *(const float4*)&x[(size_t)n * IN_F + k4 * 4];
    float* p = &xs[nn][k4 * 4];
    p[0] = v.x; p[1] = v.y; p[2] = v.z; p[3] = v.w;
  }
  __syncthreads();
  int lane = t & 63;
  int rr = __builtin_amdgcn_readfirstlane(t >> 6);    // wave-uniform relation -> SGPR
  const float* __restrict__ Wr = W1 + (size_t)rr * (IN_F * HID);
  const float* xrow = &xs[lane][0];
  float acc[HID];
#pragma unroll
  for (int j = 0; j < HID; j++) acc[j] = 0.f;
#pragma unroll 4
  for (int k4 = 0; k4 < IN_F / 4; k4++) {
    float x0 = xrow[k4 * 4 + 0];
    float x1 = xrow[k4 * 4 + 1];
    float x2 = xrow[k4 * 4 + 2];
    float x3 = xrow[k4 * 4 + 3];
    const float* wk = &Wr[(k4 * 4) * HID];            // uniform address -> s_load
#pragma unroll
    for (int j = 0; j < HID; j++) acc[j] += x0 * wk[j];
#pragma unroll
    for (int j = 0; j < HID; j++) acc[j] += x1 * wk[HID + j];
#pragma unroll
    for (int j = 0; j < HID; j++) acc[j] += x2 * wk[2 * HID + j];
#pragma unroll
    for (int j = 0; j < HID; j++) acc[j] += x3 * wk[3 * HID + j];
  }
  int n = n0 + lane;
  if (n < N_NODES) {
    float s = rs_o[(size_t)rr * N_NODES + n];
    float* o = &hw[((size_t)rr * N_NODES + n) * HID];
#pragma unroll
    for (int j4 = 0; j4 < HID / 4; j4++) {
      float4 v = make_float4(acc[j4 * 4] * s, acc[j4 * 4 + 1] * s, acc[j4 * 4 + 2] * s, acc[j4 * 4 + 3] * s);
      *(float4*)&o[j4 * 4] = v;
    }
  }
}

// ---- Fused layer-2 projection: relu(acc1 + sum_b1) staged once; wave w = relation w. ----
__global__ __launch_bounds__(512, 8) void proj2_fused(const float* __restrict__ acc1, const float* __restrict__ b1,
                                                      const float* __restrict__ W2, const float* __restrict__ rs_o,
                                                      float* __restrict__ hw) {
  __shared__ float hs[FT][HID + 1];    // stride 33: conflict-free b32
  int t = threadIdx.x;
  int n0 = blockIdx.x * FT;
  {
    int nn = t >> 3, j4 = t & 7;       // 512 threads = 64 nodes x 8 float4
    int n = n0 + nn;
    float4 v = make_float4(0.f, 0.f, 0.f, 0.f);
    if (n < N_NODES) v = *(const float4*)&acc1[(size_t)n * HID + j4 * 4];
    float4 sb = make_float4(0.f, 0.f, 0.f, 0.f);
#pragma unroll
    for (int q = 0; q < N_REL; q++) {
      const float* bq = &b1[q * HID + j4 * 4];
      sb.x += bq[0]; sb.y += bq[1]; sb.z += bq[2]; sb.w += bq[3];
    }
    float* p = &hs[nn][j4 * 4];
    p[0] = fmaxf(v.x + sb.x, 0.f); p[1] = fmaxf(v.y + sb.y, 0.f);
    p[2] = fmaxf(v.z + sb.z, 0.f); p[3] = fmaxf(v.w + sb.w, 0.f);
  }
  __syncthreads();
  int lane = t & 63;
  int rr = __builtin_amdgcn_readfirstlane(t >> 6);
  const float* __restrict__ Wr = W2 + (size_t)rr * (HID * HID);
  const float* hrow = &hs[lane][0];
  float acc[HID];
#pragma unroll
  for (int j = 0; j < HID; j++) acc[j] = 0.f;
#pragma unroll
  for (int k = 0; k < HID; k++) {
    float hv = hrow[k];
    const float* wk = &Wr[k * HID];                   // uniform -> s_load
#pragma unroll
    for (int j = 0; j < HID; j++) acc[j] += hv * wk[j];
  }
  int n = n0 + lane;
  if (n < N_NODES) {
    float s = rs_o[(size_t)rr * N_NODES + n];
    float* o = &hw[((size_t)rr * N_NODES + n) * HID];
#pragma unroll
    for (int j4 = 0; j4 < HID / 4; j4++) {
      float4 v = make_float4(acc[j4 * 4] * s, acc[j4 * 4 + 1] * s, acc[j4 * 4 + 2] * s, acc[j4 * 4 + 3] * s);
      *(float4*)&o[j4 * 4] = v;
    }
  }
}

// ---- Tier-3 per-relation projection kernels (fallback) ----
__global__ __launch_bounds__(256) void proj1_kernel(const float* __restrict__ x, const float* __restrict__ W1r0,
                                                    const float* __restrict__ rs_o, float* __restrict__ hw,
                                                    int n0, int n1, int hw_nodes) {
  int rr = blockIdx.y;
  int nb = n0 + blockIdx.x * TILE;
  int t = threadIdx.x;
  __shared__ float xs[TILE][KC + 4];
  const float* __restrict__ Wr = W1r0 + (size_t)rr * (IN_F * HID);
  float acc[HID];
#pragma unroll
  for (int j = 0; j < HID; j++) acc[j] = 0.f;
  for (int kc = 0; kc < IN_F; kc += KC) {
    __syncthreads();
#pragma unroll
    for (int i = 0; i < (TILE * KC / 4) / 256; i++) {
      int q = t + i * 256;
      int nn = q >> 3, k4 = q & 7;
      int n = nb + nn;
      float4 v = make_float4(0.f, 0.f, 0.f, 0.f);
      if (n < n1) v = *(const float4*)&x[(size_t)n * IN_F + kc + k4 * 4];
      *(float4*)&xs[nn][k4 * 4] = v;
    }
    __syncthreads();
#pragma unroll
    for (int k4 = 0; k4 < KC / 4; k4++) {
      float4 xv = *(const float4*)&xs[t][k4 * 4];
      const float* wk = &Wr[(kc + k4 * 4) * HID];
#pragma unroll
      for (int j = 0; j < HID; j++) acc[j] += xv.x * wk[j];
#pragma unroll
      for (int j = 0; j < HID; j++) acc[j] += xv.y * wk[HID + j];
#pragma unroll
      for (int j = 0; j < HID; j++) acc[j] += xv.z * wk[2 * HID + j];
#pragma unroll
      for (int j = 0; j < HID; j++) acc[j] += xv.w * wk[3 * HID + j];
    }
  }
  int n = nb + t;
  if (n < n1) {
    float s = rs_o[(size_t)rr * N_NODES + n];
    float* o = &hw[((size_t)rr * hw_nodes + (n - n0)) * HID];
#pragma unroll
    for (int j4 = 0; j4 < HID / 4; j4++) {
      float4 v = make_float4(acc[j4 * 4] * s, acc[j4 * 4 + 1] * s, acc[j4 * 4 + 2] * s, acc[j4 * 4 + 3] * s);
      *(float4*)&o[j4 * 4] = v;
    }
  }
}

__global__ __launch_bounds__(256) void proj2_kernel(const float* __restrict__ acc1, const float* __restrict__ b1,
                                                    const float* __restrict__ W2r0, const float* __restrict__ rs_o,
                                                    float* __restrict__ hw, int n0, int n1, int hw_nodes) {
  int n = n0 + blockIdx.x * 256 + threadIdx.x;
  if (n >= n1) return;
  int rr = blockIdx.y;
  float h1[HID];
#pragma unroll
  for (int j4 = 0; j4 < HID / 4; j4++) {
    float4 v = *(const float4*)&acc1[(size_t)n * HID + j4 * 4];
    h1[j4 * 4 + 0] = v.x; h1[j4 * 4 + 1] = v.y; h1[j4 * 4 + 2] = v.z; h1[j4 * 4 + 3] = v.w;
  }
#pragma unroll
  for (int j = 0; j < HID; j++) {
    float sb = 0.f;
#pragma unroll
    for (int q = 0; q < N_REL; q++) sb += b1[q * HID + j];
    h1[j] = fmaxf(h1[j] + sb, 0.f);
  }
  const float* __restrict__ Wr = W2r0 + (size_t)rr * (HID * HID);
  float acc[HID];
#pragma unroll
  for (int j = 0; j < HID; j++) acc[j] = 0.f;
#pragma unroll
  for (int k = 0; k < HID; k++) {
    float hv = h1[k];
#pragma unroll
    for (int j = 0; j < HID; j++) acc[j] += hv * Wr[k * HID + j];
  }
  float s = rs_o[(size_t)rr * N_NODES + n];
  float* o = &hw[((size_t)rr * hw_nodes + (n - n0)) * HID];
#pragma unroll
  for (int j4 = 0; j4 < HID / 4; j4++) {
    float4 v = make_float4(acc[j4 * 4] * s, acc[j4 * 4 + 1] * s, acc[j4 * 4 + 2] * s, acc[j4 * 4 + 3] * s);
    *(float4*)&o[j4 * 4] = v;
  }
}

// Edge scatter: acc[d][j] += hw[rr][s-n0][j] * rs_i[rr][d] for src in [n0,n1). 32 lanes/edge.
__global__ __launch_bounds__(256) void scatter_kernel(const float* __restrict__ hw, const int* __restrict__ src,
                                                      const int* __restrict__ dst, const float* __restrict__ rs_i,
                                                      float* __restrict__ acc, int nr, int n0, int n1, int hw_nodes) {
  long i = (long)blockIdx.x * 256 + threadIdx.x;
  long total = (long)nr * N_EDGES * HID;
  if (i >= total) return;
  int j = (int)(i & (HID - 1));
  long e = i >> 5;
  int rr = (int)(e / N_EDGES);
  int ee = (int)(e - (long)rr * N_EDGES);
  int s = src[rr * N_EDGES + ee];
  if (s < n0 || s >= n1) return;
  int d = dst[rr * N_EDGES + ee];
  float v = hw[((size_t)rr * hw_nodes + (s - n0)) * HID + j] * rs_i[(size_t)rr * N_NODES + d];
  atomicAdd(&acc[(size_t)d * HID + j], v);
}

// Per-graph sum pool with LDS staging; lane = feature (conflict-free LDS atomics).
__global__ __launch_bounds__(256) void pool_kernel(const float* __restrict__ acc2, const float* __restrict__ b2,
                                                   const int* __restrict__ gid, float* __restrict__ gpool,
                                                   float* __restrict__ gcnt) {
  __shared__ float lp[N_GRAPHS * HID];
  __shared__ float lc[N_GRAPHS];
  int t = threadIdx.x;
  for (int i = t; i < N_GRAPHS * HID; i += 256) lp[i] = 0.f;
  if (t < N_GRAPHS) lc[t] = 0.f;
  __syncthreads();
  int j = t & (HID - 1);
  int grp = t >> 5;
  float sb = 0.f;
#pragma unroll
  for (int q = 0; q < N_REL; q++) sb += b2[q * HID + j];
  for (int n = blockIdx.x * 8 + grp; n < N_NODES; n += gridDim.x * 8) {
    int g = gid[n];
    float v = acc2[(size_t)n * HID + j] + sb;
    atomicAdd(&lp[g * HID + j], v);
    if (j == 0) atomicAdd(&lc[g], 1.f);
  }
  __syncthreads();
  for (int i = t; i < N_GRAPHS * HID; i += 256) atomicAdd(&gpool[i], lp[i]);
  if (t < N_GRAPHS) atomicAdd(&gcnt[t], lc[t]);
}

__global__ void final_kernel(const float* __restrict__ gpool, const float* __restrict__ gcnt,
                             const float* __restrict__ Wc, const float* __restrict__ bc,
                             float* __restrict__ out) {
  int g = threadIdx.x;
  if (g >= N_GRAPHS) return;
  float inv = 1.f / fmaxf(gcnt[g], 1.f);
  float o0 = bc[0], o1 = bc[1];
#pragma unroll
  for (int k = 0; k < HID; k++) {
    float p = gpool[g * HID + k] * inv;
    o0 += p * Wc[k * 2 + 0];
    o1 += p * Wc[k * 2 + 1];
  }
  out[g * 2 + 0] = o0;
  out[g * 2 + 1] = o1;
}

extern "C" void kernel_launch(void* const* d_in, const int* in_sizes, int n_in,
                              void* d_out, int out_size, void* d_ws, size_t ws_size,
                              hipStream_t stream) {
  const float* x  = (const float*)d_in[0];
  const int* src  = (const int*)d_in[1];
  const int* dst  = (const int*)d_in[2];
  const int* gid  = (const int*)d_in[3];
  const float* W1 = (const float*)d_in[5];
  const float* b1 = (const float*)d_in[6];
  const float* W2 = (const float*)d_in[7];
  const float* b2 = (const float*)d_in[8];
  const float* Wc = (const float*)d_in[9];
  const float* bc = (const float*)d_in[10];
  float* out = (float*)d_out;

  float* ws = (float*)d_ws;
  const size_t NF = (size_t)N_NODES * HID;
  const size_t RN = (size_t)N_REL * N_NODES;
  const size_t POOLF = N_GRAPHS * HID + N_GRAPHS;
  float* acc1  = ws;
  float* acc2  = acc1 + NF;
  float* gpool = acc2 + NF;
  float* gcnt  = gpool + N_GRAPHS * HID;
  float* rsb   = ws + (2 * NF + POOLF);
  size_t wsf = ws_size / 4;
  size_t zf = 2 * NF + POOLF;

  if (wsf >= zf + 2 * RN + N_REL * NF) {
    // ---- Tier 1: fused 8-relation projections, full hw buffer ----
    float* rs_o_all = rsb;
    float* rs_i_all = rsb + RN;
    float* hw = rsb + 2 * RN;

    size_t zb = (zf + 2 * RN) * 4; if (zb > ws_size) zb = ws_size;
    hipMemsetAsync(d_ws, 0, zb, stream);
    deg_kernel<<<(N_REL * N_EDGES + 255) / 256, 256, 0, stream>>>(src, dst, (int*)rs_o_all, (int*)rs_i_all, N_REL);
    rsqrt_kernel<<<(int)((2 * RN + 255) / 256), 256, 0, stream>>>(rs_o_all, (int)(2 * RN));

    int fblocks = (N_NODES + FT - 1) / FT;
    proj1_fused<<<fblocks, 512, 0, stream>>>(x, W1, rs_o_all, hw);
    long tot = (long)N_REL * N_EDGES * HID;
    scatter_kernel<<<(int)((tot + 255) / 256), 256, 0, stream>>>(hw, src, dst, rs_i_all, acc1,
                                                                 N_REL, 0, N_NODES, N_NODES);
    proj2_fused<<<fblocks, 512, 0, stream>>>(acc1, b1, W2, rs_o_all, hw);
    scatter_kernel<<<(int)((tot + 255) / 256), 256, 0, stream>>>(hw, src, dst, rs_i_all, acc2,
                                                                 N_REL, 0, N_NODES, N_NODES);
  } else {
    // ---- Tier 3: per-relation degrees, node-chunked hw ----
    float* rs_o = rsb;
    float* rs_i = rsb + N_NODES;
    float* hw = rsb + 2 * N_NODES;
    size_t fixed3 = zf + 2 * N_NODES;
    size_t avail = (wsf > fixed3) ? (wsf - fixed3) : 0;
    long chunk = (long)(avail / HID) & ~255L;
    if (chunk < 256) chunk = 256;
    if (chunk > N_NODES) chunk = N_NODES;

    size_t zb = zf * 4; if (zb > ws_size) zb = ws_size;
    hipMemsetAsync(d_ws, 0, zb, stream);

    for (int layer = 0; layer < 2; layer++) {
      for (int r = 0; r < N_REL; r++) {
        hipMemsetAsync(rs_o, 0, 2 * N_NODES * 4, stream);
        deg_kernel<<<(N_EDGES + 255) / 256, 256, 0, stream>>>(src + (size_t)r * N_EDGES, dst + (size_t)r * N_EDGES,
                                                              (int*)rs_o, (int*)rs_i, 1);
        rsqrt_kernel<<<(2 * N_NODES + 255) / 256, 256, 0, stream>>>(rs_o, 2 * N_NODES);
        for (long n0 = 0; n0 < N_NODES; n0 += chunk) {
          long n1 = n0 + chunk; if (n1 > N_NODES) n1 = N_NODES;
          int tiles = (int)((n1 - n0 + TILE - 1) / TILE);
          if (layer == 0)
            proj1_kernel<<<dim3(tiles, 1), 256, 0, stream>>>(x, W1 + (size_t)r * IN_F * HID, rs_o, hw,
                                                             (int)n0, (int)n1, (int)chunk);
          else
            proj2_kernel<<<dim3(tiles, 1), 256, 0, stream>>>(acc1, b1, W2 + (size_t)r * HID * HID, rs_o, hw,
                                                             (int)n0, (int)n1, (int)chunk);
          long tot = (long)N_EDGES * HID;
          scatter_kernel<<<(int)((tot + 255) / 256), 256, 0, stream>>>(hw, src + (size_t)r * N_EDGES,
                                                                       dst + (size_t)r * N_EDGES, rs_i,
                                                                       layer == 0 ? acc1 : acc2,
                                                                       1, (int)n0, (int)n1, (int)chunk);
        }
      }
    }
  }

  pool_kernel<<<256, 256, 0, stream>>>(acc2, b2, gid, gpool, gcnt);
  final_kernel<<<1, 64, 0, stream>>>(gpool, gcnt, Wc, bc, out);
}

// Round 5
// 422.729 us; speedup vs baseline: 2.1141x; 1.0998x over previous
//
#include <hip/hip_runtime.h>

// RGCN vulnerability classifier, fp32 in/out, MI355X.
// Algebraic fusion: hw[r] = diag(rs_o[r]) (x @ W1[r])  =>  ONE GEMM Y = x @ Wcat,
// with rs_o[r][s]*rs_i[r][d] folded into the edge scatter.
// Projections run as bf16 MFMA GEMMs (threshold 1.6e-2 >> expected ~1e-3 bf16 error).
// degrees -> rsqrt -> cast/prep -> GEMM1 -> scatter -> prep_H -> GEMM2 -> scatter
//   -> mean pool -> 32x2 classifier.  Tier-3 fp32 fallback for small ws.

#define N_NODES 100000
#define N_REL   8
#define N_EDGES 80000
#define IN_F    128
#define HID     32
#define N_GRAPHS 64
#define NCAT    (N_REL * HID)   // 256 concatenated output cols

constexpr int TILE = 256;   // tier-3 projection block
constexpr int KC   = 32;

typedef __attribute__((ext_vector_type(8))) short bf16x8;   // 8 bf16 = 4 VGPRs
typedef __attribute__((ext_vector_type(4))) float f32x4;

__device__ __forceinline__ ushort f2bf(float v) {
  unsigned u = __builtin_bit_cast(unsigned, v);
  u = (u + 0x7fffu + ((u >> 16) & 1u)) >> 16;   // RNE
  return (ushort)u;
}
__device__ __forceinline__ float bf2f(ushort h) {
  unsigned u = ((unsigned)h) << 16;
  return __builtin_bit_cast(float, u);
}

__global__ __launch_bounds__(256) void deg_kernel(const int* __restrict__ src, const int* __restrict__ dst,
                                                  int* __restrict__ dego, int* __restrict__ degi, int n_rel) {
  int i = blockIdx.x * 256 + threadIdx.x;
  if (i < n_rel * N_EDGES) {
    int r = i / N_EDGES;
    atomicAdd(&dego[r * N_NODES + src[i]], 1);
    atomicAdd(&degi[r * N_NODES + dst[i]], 1);
  }
}

__global__ __launch_bounds__(256) void rsqrt_kernel(float* __restrict__ p, int count) {
  int i = blockIdx.x * 256 + threadIdx.x;
  if (i < count) {
    int d = ((const int*)p)[i];
    p[i] = rsqrtf((float)(d < 1 ? 1 : d));
  }
}

// x fp32 -> bf16, 4 elems/thread
__global__ __launch_bounds__(256) void cast_x_kernel(const float* __restrict__ x, ushort* __restrict__ xbf) {
  long i = (blockIdx.x * 256L + threadIdx.x) * 4;
  if (i >= (long)N_NODES * IN_F) return;
  float4 v = *(const float4*)&x[i];
  ushort4 o; o.x = f2bf(v.x); o.y = f2bf(v.y); o.z = f2bf(v.z); o.w = f2bf(v.w);
  *(ushort4*)&xbf[i] = o;
}

// Wt1[n][k] = bf16(W1[r][k][j]), n = r*32+j  (col-major-K for MFMA B-fragments)
// Wt2[n][k] = bf16(W2[r][k][j])
__global__ __launch_bounds__(256) void prep_w_kernel(const float* __restrict__ W1, const float* __restrict__ W2,
                                                     ushort* __restrict__ Wt1, ushort* __restrict__ Wt2) {
  int i = blockIdx.x * 256 + threadIdx.x;
  if (i < NCAT * IN_F) {
    int n = i >> 7, k = i & 127;
    int r = n >> 5, j = n & 31;
    Wt1[i] = f2bf(W1[r * (IN_F * HID) + k * HID + j]);
  } else {
    int q = i - NCAT * IN_F;
    if (q < NCAT * HID) {
      int n = q >> 5, k = q & 31;
      int r = n >> 5, j = n & 31;
      Wt2[q] = f2bf(W2[r * (HID * HID) + k * HID + j]);
    }
  }
}

// H = bf16(relu(acc1 + sum_r b1[r]))
__global__ __launch_bounds__(256) void prep_h_kernel(const float* __restrict__ acc1, const float* __restrict__ b1,
                                                     ushort* __restrict__ H) {
  long i = blockIdx.x * 256L + threadIdx.x;
  if (i >= (long)N_NODES * HID) return;
  int j = (int)(i & (HID - 1));
  float sb = 0.f;
#pragma unroll
  for (int q = 0; q < N_REL; q++) sb += b1[q * HID + j];
  H[i] = f2bf(fmaxf(acc1[i] + sb, 0.f));
}

// MFMA GEMM: Y[M x 256] = A[M x K] @ W[K x 256], A and Bt(=[256 x K]) bf16, Y bf16.
// One wave = 16 rows x all 256 cols (16 acc tiles, 64 MFMAs at K=128). No LDS, no barriers;
// Bt (<=64 KB) is L1/L2-resident. A-frag: lane holds A[m=lane&15][k=quad*8+j] (b128 load);
// B-frag mirrors it on Bt rows (m97 B^T convention). D: row=quad*4+i, col=lane&15 (m89).
template<int K>
__global__ __launch_bounds__(256) void gemm_mfma(const ushort* __restrict__ A, const ushort* __restrict__ Bt,
                                                 ushort* __restrict__ Y, int M) {
  int wave = threadIdx.x >> 6;
  int lane = threadIdx.x & 63;
  int m0 = (blockIdx.x * 4 + wave) * 16;
  if (m0 >= M) return;
  int row = lane & 15, quad = lane >> 4;
  f32x4 acc[16];
#pragma unroll
  for (int nt = 0; nt < 16; nt++) acc[nt] = (f32x4){0.f, 0.f, 0.f, 0.f};
#pragma unroll
  for (int kq = 0; kq < K / 32; kq++) {
    bf16x8 a = *(const bf16x8*)&A[(size_t)(m0 + row) * K + kq * 32 + quad * 8];
#pragma unroll
    for (int nt = 0; nt < 16; nt++) {
      bf16x8 b = *(const bf16x8*)&Bt[(size_t)(nt * 16 + row) * K + kq * 32 + quad * 8];
      acc[nt] = __builtin_amdgcn_mfma_f32_16x16x32_bf16(a, b, acc[nt], 0, 0, 0);
    }
  }
#pragma unroll
  for (int nt = 0; nt < 16; nt++) {
#pragma unroll
    for (int i = 0; i < 4; i++) {
      int m = m0 + quad * 4 + i;
      int n = nt * 16 + row;
      Y[(size_t)m * NCAT + n] = f2bf(acc[nt][i]);
    }
  }
}

// Edge scatter from bf16 Y: acc[d][j] += Y[s][r*32+j] * rs_o[r][s] * rs_i[r][d]. 32 lanes/edge.
__global__ __launch_bounds__(256) void scatter_bf16(const ushort* __restrict__ Y, const int* __restrict__ src,
                                                    const int* __restrict__ dst, const float* __restrict__ rs_o,
                                                    const float* __restrict__ rs_i, float* __restrict__ acc) {
  long i = blockIdx.x * 256L + threadIdx.x;
  if (i >= (long)N_REL * N_EDGES * HID) return;
  int j = (int)(i & (HID - 1));
  long e = i >> 5;                       // flat edge id = r*N_EDGES + ee
  int r = (int)(e / N_EDGES);
  int s = src[e];
  int d = dst[e];
  float v = bf2f(Y[(size_t)s * NCAT + r * HID + j]) * rs_o[(size_t)r * N_NODES + s] * rs_i[(size_t)r * N_NODES + d];
  atomicAdd(&acc[(size_t)d * HID + j], v);
}

// ---- Tier-3 fp32 fallback kernels (small ws) ----
__global__ __launch_bounds__(256) void proj1_kernel(const float* __restrict__ x, const float* __restrict__ W1r0,
                                                    const float* __restrict__ rs_o, float* __restrict__ hw,
                                                    int n0, int n1, int hw_nodes) {
  int rr = blockIdx.y;
  int nb = n0 + blockIdx.x * TILE;
  int t = threadIdx.x;
  __shared__ float xs[TILE][KC + 4];
  const float* __restrict__ Wr = W1r0 + (size_t)rr * (IN_F * HID);
  float acc[HID];
#pragma unroll
  for (int j = 0; j < HID; j++) acc[j] = 0.f;
  for (int kc = 0; kc < IN_F; kc += KC) {
    __syncthreads();
#pragma unroll
    for (int i = 0; i < (TILE * KC / 4) / 256; i++) {
      int q = t + i * 256;
      int nn = q >> 3, k4 = q & 7;
      int n = nb + nn;
      float4 v = make_float4(0.f, 0.f, 0.f, 0.f);
      if (n < n1) v = *(const float4*)&x[(size_t)n * IN_F + kc + k4 * 4];
      *(float4*)&xs[nn][k4 * 4] = v;
    }
    __syncthreads();
#pragma unroll
    for (int k4 = 0; k4 < KC / 4; k4++) {
      float4 xv = *(const float4*)&xs[t][k4 * 4];
      const float* wk = &Wr[(kc + k4 * 4) * HID];
#pragma unroll
      for (int j = 0; j < HID; j++) acc[j] += xv.x * wk[j];
#pragma unroll
      for (int j = 0; j < HID; j++) acc[j] += xv.y * wk[HID + j];
#pragma unroll
      for (int j = 0; j < HID; j++) acc[j] += xv.z * wk[2 * HID + j];
#pragma unroll
      for (int j = 0; j < HID; j++) acc[j] += xv.w * wk[3 * HID + j];
    }
  }
  int n = nb + t;
  if (n < n1) {
    float s = rs_o[(size_t)rr * N_NODES + n];
    float* o = &hw[((size_t)rr * hw_nodes + (n - n0)) * HID];
#pragma unroll
    for (int j4 = 0; j4 < HID / 4; j4++) {
      float4 v = make_float4(acc[j4 * 4] * s, acc[j4 * 4 + 1] * s, acc[j4 * 4 + 2] * s, acc[j4 * 4 + 3] * s);
      *(float4*)&o[j4 * 4] = v;
    }
  }
}

__global__ __launch_bounds__(256) void proj2_kernel(const float* __restrict__ acc1, const float* __restrict__ b1,
                                                    const float* __restrict__ W2r0, const float* __restrict__ rs_o,
                                                    float* __restrict__ hw, int n0, int n1, int hw_nodes) {
  int n = n0 + blockIdx.x * 256 + threadIdx.x;
  if (n >= n1) return;
  int rr = blockIdx.y;
  float h1[HID];
#pragma unroll
  for (int j4 = 0; j4 < HID / 4; j4++) {
    float4 v = *(const float4*)&acc1[(size_t)n * HID + j4 * 4];
    h1[j4 * 4 + 0] = v.x; h1[j4 * 4 + 1] = v.y; h1[j4 * 4 + 2] = v.z; h1[j4 * 4 + 3] = v.w;
  }
#pragma unroll
  for (int j = 0; j < HID; j++) {
    float sb = 0.f;
#pragma unroll
    for (int q = 0; q < N_REL; q++) sb += b1[q * HID + j];
    h1[j] = fmaxf(h1[j] + sb, 0.f);
  }
  const float* __restrict__ Wr = W2r0 + (size_t)rr * (HID * HID);
  float acc[HID];
#pragma unroll
  for (int j = 0; j < HID; j++) acc[j] = 0.f;
#pragma unroll
  for (int k = 0; k < HID; k++) {
    float hv = h1[k];
#pragma unroll
    for (int j = 0; j < HID; j++) acc[j] += hv * Wr[k * HID + j];
  }
  float s = rs_o[(size_t)rr * N_NODES + n];
  float* o = &hw[((size_t)rr * hw_nodes + (n - n0)) * HID];
#pragma unroll
  for (int j4 = 0; j4 < HID / 4; j4++) {
    float4 v = make_float4(acc[j4 * 4] * s, acc[j4 * 4 + 1] * s, acc[j4 * 4 + 2] * s, acc[j4 * 4 + 3] * s);
    *(float4*)&o[j4 * 4] = v;
  }
}

__global__ __launch_bounds__(256) void scatter_kernel(const float* __restrict__ hw, const int* __restrict__ src,
                                                      const int* __restrict__ dst, const float* __restrict__ rs_i,
                                                      float* __restrict__ acc, int nr, int n0, int n1, int hw_nodes) {
  long i = (long)blockIdx.x * 256 + threadIdx.x;
  long total = (long)nr * N_EDGES * HID;
  if (i >= total) return;
  int j = (int)(i & (HID - 1));
  long e = i >> 5;
  int rr = (int)(e / N_EDGES);
  int ee = (int)(e - (long)rr * N_EDGES);
  int s = src[rr * N_EDGES + ee];
  if (s < n0 || s >= n1) return;
  int d = dst[rr * N_EDGES + ee];
  float v = hw[((size_t)rr * hw_nodes + (s - n0)) * HID + j] * rs_i[(size_t)rr * N_NODES + d];
  atomicAdd(&acc[(size_t)d * HID + j], v);
}

// Per-graph sum pool with LDS staging; lane = feature (conflict-free LDS atomics).
__global__ __launch_bounds__(256) void pool_kernel(const float* __restrict__ acc2, const float* __restrict__ b2,
                                                   const int* __restrict__ gid, float* __restrict__ gpool,
                                                   float* __restrict__ gcnt) {
  __shared__ float lp[N_GRAPHS * HID];
  __shared__ float lc[N_GRAPHS];
  int t = threadIdx.x;
  for (int i = t; i < N_GRAPHS * HID; i += 256) lp[i] = 0.f;
  if (t < N_GRAPHS) lc[t] = 0.f;
  __syncthreads();
  int j = t & (HID - 1);
  int grp = t >> 5;
  float sb = 0.f;
#pragma unroll
  for (int q = 0; q < N_REL; q++) sb += b2[q * HID + j];
  for (int n = blockIdx.x * 8 + grp; n < N_NODES; n += gridDim.x * 8) {
    int g = gid[n];
    float v = acc2[(size_t)n * HID + j] + sb;
    atomicAdd(&lp[g * HID + j], v);
    if (j == 0) atomicAdd(&lc[g], 1.f);
  }
  __syncthreads();
  for (int i = t; i < N_GRAPHS * HID; i += 256) atomicAdd(&gpool[i], lp[i]);
  if (t < N_GRAPHS) atomicAdd(&gcnt[t], lc[t]);
}

__global__ void final_kernel(const float* __restrict__ gpool, const float* __restrict__ gcnt,
                             const float* __restrict__ Wc, const float* __restrict__ bc,
                             float* __restrict__ out) {
  int g = threadIdx.x;
  if (g >= N_GRAPHS) return;
  float inv = 1.f / fmaxf(gcnt[g], 1.f);
  float o0 = bc[0], o1 = bc[1];
#pragma unroll
  for (int k = 0; k < HID; k++) {
    float p = gpool[g * HID + k] * inv;
    o0 += p * Wc[k * 2 + 0];
    o1 += p * Wc[k * 2 + 1];
  }
  out[g * 2 + 0] = o0;
  out[g * 2 + 1] = o1;
}

extern "C" void kernel_launch(void* const* d_in, const int* in_sizes, int n_in,
                              void* d_out, int out_size, void* d_ws, size_t ws_size,
                              hipStream_t stream) {
  const float* x  = (const float*)d_in[0];
  const int* src  = (const int*)d_in[1];
  const int* dst  = (const int*)d_in[2];
  const int* gid  = (const int*)d_in[3];
  const float* W1 = (const float*)d_in[5];
  const float* b1 = (const float*)d_in[6];
  const float* W2 = (const float*)d_in[7];
  const float* b2 = (const float*)d_in[8];
  const float* Wc = (const float*)d_in[9];
  const float* bc = (const float*)d_in[10];
  float* out = (float*)d_out;

  float* ws = (float*)d_ws;
  const size_t NF = (size_t)N_NODES * HID;           // 3.2M
  const size_t RN = (size_t)N_REL * N_NODES;         // 800k
  const size_t POOLF = N_GRAPHS * HID + N_GRAPHS;
  float* acc1  = ws;
  float* acc2  = acc1 + NF;
  float* gpool = acc2 + NF;
  float* gcnt  = gpool + N_GRAPHS * HID;
  float* rsb   = ws + (2 * NF + POOLF);
  size_t wsf = ws_size / 4;
  size_t zf = 2 * NF + POOLF;

  if (wsf >= zf + 2 * RN + N_REL * NF) {
    // ---- Tier 1: bf16 MFMA GEMM path (footprint identical to round-4 tier-1: ~134 MB) ----
    float* rs_o_all = rsb;                     // [R][N]
    float* rs_i_all = rsb + RN;                // [R][N]
    float* hwreg = rsb + 2 * RN;               // 8*NF floats, carved into bf16 buffers:
    ushort* Ybf = (ushort*)hwreg;                                        // N*256 halfs (=12.8M f)
    ushort* xbf = (ushort*)(hwreg + (size_t)N_NODES * NCAT / 2);         // N*128 halfs (=6.4M f)
    ushort* Hbf = (ushort*)(hwreg + (size_t)N_NODES * NCAT / 2 + (size_t)N_NODES * IN_F / 2);  // N*32 halfs
    ushort* Wt1 = (ushort*)((float*)Hbf + (size_t)N_NODES * HID / 2);    // 256*128 halfs
    ushort* Wt2 = Wt1 + NCAT * IN_F;                                     // 256*32 halfs

    size_t zb = (zf + 2 * RN) * 4; if (zb > ws_size) zb = ws_size;
    hipMemsetAsync(d_ws, 0, zb, stream);
    deg_kernel<<<(N_REL * N_EDGES + 255) / 256, 256, 0, stream>>>(src, dst, (int*)rs_o_all, (int*)rs_i_all, N_REL);
    rsqrt_kernel<<<(int)((2 * RN + 255) / 256), 256, 0, stream>>>(rs_o_all, (int)(2 * RN));

    cast_x_kernel<<<(int)(((size_t)N_NODES * IN_F / 4 + 255) / 256), 256, 0, stream>>>(x, xbf);
    prep_w_kernel<<<(NCAT * IN_F + NCAT * HID + 255) / 256, 256, 0, stream>>>(W1, W2, Wt1, Wt2);

    int gblocks = (N_NODES / 16 + 3) / 4;      // 6250 row-tiles, 4 waves/block
    gemm_mfma<IN_F><<<gblocks, 256, 0, stream>>>(xbf, Wt1, Ybf, N_NODES);
    long tot = (long)N_REL * N_EDGES * HID;
    scatter_bf16<<<(int)((tot + 255) / 256), 256, 0, stream>>>(Ybf, src, dst, rs_o_all, rs_i_all, acc1);

    prep_h_kernel<<<(int)((NF + 255) / 256), 256, 0, stream>>>(acc1, b1, Hbf);
    gemm_mfma<HID><<<gblocks, 256, 0, stream>>>(Hbf, Wt2, Ybf, N_NODES);
    scatter_bf16<<<(int)((tot + 255) / 256), 256, 0, stream>>>(Ybf, src, dst, rs_o_all, rs_i_all, acc2);
  } else {
    // ---- Tier 3: fp32 per-relation fallback, node-chunked hw ----
    float* rs_o = rsb;
    float* rs_i = rsb + N_NODES;
    float* hw = rsb + 2 * N_NODES;
    size_t fixed3 = zf + 2 * N_NODES;
    size_t avail = (wsf > fixed3) ? (wsf - fixed3) : 0;
    long chunk = (long)(avail / HID) & ~255L;
    if (chunk < 256) chunk = 256;
    if (chunk > N_NODES) chunk = N_NODES;

    size_t zb = zf * 4; if (zb > ws_size) zb = ws_size;
    hipMemsetAsync(d_ws, 0, zb, stream);

    for (int layer = 0; layer < 2; layer++) {
      for (int r = 0; r < N_REL; r++) {
        hipMemsetAsync(rs_o, 0, 2 * N_NODES * 4, stream);
        deg_kernel<<<(N_EDGES + 255) / 256, 256, 0, stream>>>(src + (size_t)r * N_EDGES, dst + (size_t)r * N_EDGES,
                                                              (int*)rs_o, (int*)rs_i, 1);
        rsqrt_kernel<<<(2 * N_NODES + 255) / 256, 256, 0, stream>>>(rs_o, 2 * N_NODES);
        for (long n0 = 0; n0 < N_NODES; n0 += chunk) {
          long n1 = n0 + chunk; if (n1 > N_NODES) n1 = N_NODES;
          int tiles = (int)((n1 - n0 + TILE - 1) / TILE);
          if (layer == 0)
            proj1_kernel<<<dim3(tiles, 1), 256, 0, stream>>>(x, W1 + (size_t)r * IN_F * HID, rs_o, hw,
                                                             (int)n0, (int)n1, (int)chunk);
          else
            proj2_kernel<<<dim3(tiles, 1), 256, 0, stream>>>(acc1, b1, W2 + (size_t)r * HID * HID, rs_o, hw,
                                                             (int)n0, (int)n1, (int)chunk);
          long tot = (long)N_EDGES * HID;
          scatter_kernel<<<(int)((tot + 255) / 256), 256, 0, stream>>>(hw, src + (size_t)r * N_EDGES,
                                                                       dst + (size_t)r * N_EDGES, rs_i,
                                                                       layer == 0 ? acc1 : acc2,
                                                                       1, (int)n0, (int)n1, (int)chunk);
        }
      }
    }
  }

  pool_kernel<<<256, 256, 0, stream>>>(acc2, b2, gid, gpool, gcnt);
  final_kernel<<<1, 64, 0, stream>>>(gpool, gcnt, Wc, bc, out);
}